// Round 9
// baseline (184.003 us; speedup 1.0000x reference)
//
#include <hip/hip_runtime.h>
#include <hip/hip_bf16.h>

// Problem constants (from reference)
#define NN  100000   // nodes
#define DF  128      // feature dim per table
#define HD  64       // hidden dim
#define NS  250000   // samples

// ---------------------------------------------------------------------------
// Algebra (R6/R8): out[s] = w2 . relu(u'[src] + v[dst]), where
//   Pn = [in1|in2] @ B  (M=100000, K=256, N=128), bf16 (25.6 MB, L3-resident)
//   Pn[n][0:64]  = u'[n] = in1[n]@W1a + in2[n]@W1c + b1   (b1 folded)
//   Pn[n][64:128]= v [n] = in1[n]@W1b + in2[n]@W1d
//   B[k][n] = w1[(k>=128)*256 + (n>=64)*128 + (k&127)][n&63]
//
// R9: phase-1 rebuilt LDS-free & sync-free (R5-R8 plateaued at ~44 us,
// MfmaUtil 5%, VALUBusy 7% -> stall-dominated sync-chained blocks).
// Operand swap: weights -> A-operand (frag layout A[m=lane&15][k] is
// index-identical to B-frag, so prep's Bf works as-is); node rows -> B-operand
// (lane n reads its own row's 32B k-window directly from global; per k-step a
// wave touches 16 rows x one exact 128B line each). D: col=lane&15 = node row,
// row=quad*4+reg = P-col -> 4 consecutive cols packed into one b64 store.
//
// Verified MFMA layouts (gfx950, learn_hip m89/m91):
//   A-frag: A[m=lane&15][k=(lane>>4)*8+j]   B-frag: B[n=lane&15][k=...]
//   C/D   : col=lane&15 (B-side), row=(lane>>4)*4+reg (A-side)
// LESSONS: train_sample is int32 on device; NS%32=16 -> clamp+predicate;
// ~75 us of wall is harness reset overhead (input restore + 268MB ws fill).
// ---------------------------------------------------------------------------

typedef __attribute__((ext_vector_type(8))) short bfrag;   // 8 bf16 = 4 VGPRs
typedef __attribute__((ext_vector_type(4))) float ffrag;   // 4 fp32 acc

__device__ __forceinline__ unsigned short bf16bits(float f) {
    __hip_bfloat16 b = __float2bfloat16(f);   // RNE
    return *(unsigned short*)&b;
}
__device__ __forceinline__ unsigned pack2(float a, float b) {
    return (unsigned)bf16bits(a) | ((unsigned)bf16bits(b) << 16);
}
__device__ __forceinline__ float bflo(unsigned u) {
    union { unsigned i; float f; } c; c.i = u << 16; return c.f;
}
__device__ __forceinline__ float bfhi(unsigned u) {
    union { unsigned i; float f; } c; c.i = u & 0xffff0000u; return c.f;
}

// ---- prep: pack B (256x128) into fragment-ordered bf16; pack w2 bf16 ----
// Bf[tn][ks][lane][j]: n = tn*16+(lane&15), k = ks*32+(lane>>4)*8+j
__global__ __launch_bounds__(256) void prep_w1_kernel(
    const float* __restrict__ w1, const float* __restrict__ w2,
    unsigned short* __restrict__ Bf, unsigned short* __restrict__ w2bf)
{
    const int gid = blockIdx.x * 256 + threadIdx.x;
    if (gid >= 4096) {
        const int j = gid - 4096;
        if (j < HD) w2bf[j] = bf16bits(w2[j]);
        return;
    }
    const int lane = gid & 63;
    const int ks   = (gid >> 6) & 7;
    const int tn   = gid >> 9;

    const int n     = tn * 16 + (lane & 15);
    const int kbase = ks * 32 + (lane >> 4) * 8;
    const int col   = n & 63;

    uint4 u;
    unsigned p[4];
    #pragma unroll
    for (int jp = 0; jp < 4; ++jp) {
        float v[2];
        #pragma unroll
        for (int h = 0; h < 2; ++h) {
            const int k = kbase + jp * 2 + h;
            const int row = ((k >= 128) ? 256 : 0) + ((n >= 64) ? 128 : 0) + (k & 127);
            v[h] = w1[(size_t)row * HD + col];
        }
        p[jp] = pack2(v[0], v[1]);
    }
    u.x = p[0]; u.y = p[1]; u.z = p[2]; u.w = p[3];
    *(uint4*)(Bf + (size_t)gid * 8) = u;
}

// ---- phase 1: LDS-free streaming MFMA GEMM ----
// grid = 3125 (32 node rows/block), block = 256 = 4 waves.
// Wave w: P-cols [32w, 32w+32) (2 16-col tiles), both 16-row groups.
// Weight frags (A-operand) loaded once into 64 VGPRs; node frags (B-operand)
// streamed from global; no LDS, no __syncthreads.
__global__ __launch_bounds__(256) void node_gemm_mfma(
    const float* __restrict__ in1,
    const float* __restrict__ in2,
    const unsigned short* __restrict__ Bf,
    const float* __restrict__ b1,
    unsigned short* __restrict__ Pn)         // [NN][128] bf16
{
    const int t    = threadIdx.x;
    const int lane = t & 63;
    const int w    = t >> 6;
    const int m0   = blockIdx.x * 32;

    // ---- weight frags: 2 tiles x 8 ks, loaded once (L2-hot) ----
    bfrag wf[2][8];
    #pragma unroll
    for (int ti = 0; ti < 2; ++ti) {
        const int tn = w * 2 + ti;
        #pragma unroll
        for (int ks = 0; ks < 8; ++ks)
            wf[ti][ks] = *(const bfrag*)(Bf + ((size_t)(tn * 8 + ks) * 64 + lane) * 8);
    }

    // ---- b1 fold values (cols < 64 only, i.e. waves 0,1) ----
    const int rq = lane >> 4;
    float4 badd[2];
    #pragma unroll
    for (int ti = 0; ti < 2; ++ti) {
        const int c0 = w * 32 + ti * 16 + rq * 4;
        badd[ti] = (w < 2) ? *(const float4*)(b1 + c0)
                           : make_float4(0.f, 0.f, 0.f, 0.f);
    }

    // ---- stream node rows: 2 rowgroups x 8 ks, MFMA as we go ----
    ffrag acc[2][2];
    #pragma unroll
    for (int rg = 0; rg < 2; ++rg) {
        acc[rg][0] = (ffrag){0.f, 0.f, 0.f, 0.f};
        acc[rg][1] = (ffrag){0.f, 0.f, 0.f, 0.f};
    }

    #pragma unroll
    for (int rg = 0; rg < 2; ++rg) {
        const int row = m0 + rg * 16 + (lane & 15);
        const float* r1 = in1 + (size_t)row * DF;
        const float* r2 = in2 + (size_t)row * DF;
        #pragma unroll
        for (int ks = 0; ks < 8; ++ks) {
            const float* src = (ks < 4) ? r1 + ks * 32 + rq * 8
                                        : r2 + (ks - 4) * 32 + rq * 8;
            const float4 f0 = *(const float4*)(src);
            const float4 f1 = *(const float4*)(src + 4);
            bfrag nf;
            uint4* nu = (uint4*)&nf;
            nu->x = pack2(f0.x, f0.y); nu->y = pack2(f0.z, f0.w);
            nu->z = pack2(f1.x, f1.y); nu->w = pack2(f1.z, f1.w);
            acc[rg][0] = __builtin_amdgcn_mfma_f32_16x16x32_bf16(wf[0][ks], nf, acc[rg][0], 0, 0, 0);
            acc[rg][1] = __builtin_amdgcn_mfma_f32_16x16x32_bf16(wf[1][ks], nf, acc[rg][1], 0, 0, 0);
        }
    }

    // ---- epilogue: +b1, pack 4 consecutive cols -> one b64 store each ----
    #pragma unroll
    for (int rg = 0; rg < 2; ++rg) {
        const int nrow = m0 + rg * 16 + (lane & 15);
        #pragma unroll
        for (int ti = 0; ti < 2; ++ti) {
            const int c0 = w * 32 + ti * 16 + rq * 4;
            uint2 u;
            u.x = pack2(acc[rg][ti][0] + badd[ti].x, acc[rg][ti][1] + badd[ti].y);
            u.y = pack2(acc[rg][ti][2] + badd[ti].z, acc[rg][ti][3] + badd[ti].w);
            *(uint2*)(Pn + (size_t)nrow * 128 + c0) = u;
        }
    }
}

// ---- phase 2: out[s] = w2bf . relu(u'[src] + v[dst]) ----
// grid = 7813 (x32 samples, last clamped), block = 256.
// 8 lanes/sample, 8 cols/lane; 4 VMEM per thread (ts, u, v, w2).
__global__ __launch_bounds__(256) void edge_mlp_kernel(
    const unsigned short* __restrict__ Pn,
    const int*   __restrict__ ts,     // train_sample, int32
    const unsigned short* __restrict__ w2bf,   // 64 bf16
    float* __restrict__ out)          // (250000)
{
    const int t  = threadIdx.x;
    const int sr = blockIdx.x * 32 + (t >> 3);
    const int s  = min(sr, NS - 1);
    const int l  = t & 7;
    const int j  = l * 8;

    const int2 e = ((const int2*)ts)[s];
    const uint4 uu = *(const uint4*)(Pn + (size_t)e.x * 128 + j);       // u'+b1
    const uint4 vv = *(const uint4*)(Pn + (size_t)e.y * 128 + 64 + j);  // v
    const uint4 ww = *(const uint4*)(w2bf + j);

    float p = 0.f, x;
    x = bflo(uu.x) + bflo(vv.x); x = x > 0.f ? x : 0.f; p += x * bflo(ww.x);
    x = bfhi(uu.x) + bfhi(vv.x); x = x > 0.f ? x : 0.f; p += x * bfhi(ww.x);
    x = bflo(uu.y) + bflo(vv.y); x = x > 0.f ? x : 0.f; p += x * bflo(ww.y);
    x = bfhi(uu.y) + bfhi(vv.y); x = x > 0.f ? x : 0.f; p += x * bfhi(ww.y);
    x = bflo(uu.z) + bflo(vv.z); x = x > 0.f ? x : 0.f; p += x * bflo(ww.z);
    x = bfhi(uu.z) + bfhi(vv.z); x = x > 0.f ? x : 0.f; p += x * bfhi(ww.z);
    x = bflo(uu.w) + bflo(vv.w); x = x > 0.f ? x : 0.f; p += x * bflo(ww.w);
    x = bfhi(uu.w) + bfhi(vv.w); x = x > 0.f ? x : 0.f; p += x * bfhi(ww.w);

    p += __shfl_xor(p, 1);
    p += __shfl_xor(p, 2);
    p += __shfl_xor(p, 4);
    if (l == 0 && sr < NS) out[sr] = p;
}

extern "C" void kernel_launch(void* const* d_in, const int* in_sizes, int n_in,
                              void* d_out, int out_size, void* d_ws, size_t ws_size,
                              hipStream_t stream) {
    const float* in1 = (const float*)d_in[0];
    const float* in2 = (const float*)d_in[1];
    const int*   ts  = (const int*)  d_in[2];
    const float* w1  = (const float*)d_in[3];
    const float* b1  = (const float*)d_in[4];
    const float* w2  = (const float*)d_in[5];
    float* out = (float*)d_out;

    unsigned short* Pn = (unsigned short*)d_ws;     // 100000*128*2 = 25.6 MB
    const size_t Pbytes = (size_t)NN * 128 * sizeof(unsigned short);
    unsigned short* Bf;                             // 64 KB packed-B fragments
    unsigned short* w2bf;                           // 128 B packed w2
    if (ws_size >= Pbytes + 65536 + 128) {
        Bf   = (unsigned short*)((char*)d_ws + Pbytes);
        w2bf = (unsigned short*)((char*)d_ws + Pbytes + 65536);
    } else {
        // fallback: borrow d_out front (1 MB; fully overwritten by phase 2)
        Bf   = (unsigned short*)d_out;
        w2bf = (unsigned short*)((char*)d_out + 65536);
    }

    prep_w1_kernel<<<17, 256, 0, stream>>>(w1, w2, Bf, w2bf);
    node_gemm_mfma<<<NN / 32, 256, 0, stream>>>(in1, in2, Bf, b1, Pn);
    edge_mlp_kernel<<<(NS + 31) / 32, 256, 0, stream>>>(Pn, ts, w2bf, out);
}

// Round 10
// 160.997 us; speedup vs baseline: 1.1429x; 1.1429x over previous
//
#include <hip/hip_runtime.h>
#include <hip/hip_bf16.h>

// Problem constants (from reference)
#define NN  100000   // nodes
#define DF  128      // feature dim per table
#define HD  64       // hidden dim
#define NS  250000   // samples

// ---------------------------------------------------------------------------
// Algebra (R6/R8): out[s] = w2 . relu(u'[src] + v[dst]), where
//   Pn = [in1|in2] @ B  (M=100000, K=256, N=128), bf16 (25.6 MB, L3-resident)
//   Pn[n][0:64]  = u'[n] = in1[n]@W1a + in2[n]@W1c + b1   (b1 folded)
//   Pn[n][64:128]= v [n] = in1[n]@W1b + in2[n]@W1d
//   B[k][n] = w1[(k>=128)*256 + (n>=64)*128 + (k&127)][n&63]
//
// R10: R6 shape (16-row tiles, 6250 blocks) + async global_load_lds staging.
// R5-R8 all plateaued ~43us with every pipe <10% busy: the serialized
// global->VGPR->pack->ds_write->barrier chain per block generation. R9's
// LDS-free direct reads regressed (74us: 16-way line scatter per instr).
// Here: 16 chunks of 1KB staged async in FRAGMENT order (chunk 2ks+half,
// slot lane <-> row lane&15, cols ks*32+(lane>>4)*8+half*4), so the LDS
// destination is the hardware-mandated base+lane*16 AND readback is the
// dense ds_read_b128 pattern. cvt/pack moves after the barrier.
//
// Verified MFMA layouts (gfx950, learn_hip m89/m91):
//   A-frag: A[m=lane&15][k=(lane>>4)*8+j]   B-frag: B[n=lane&15][k=...]
//   C/D   : col=lane&15 (B/n side), row=(lane>>4)*4+reg (A/m side)
// LESSONS: train_sample is int32 on device; NS%32=16 -> clamp+predicate;
// ~75 us of wall is harness reset overhead (input restore + 268MB ws fill).
// ---------------------------------------------------------------------------

typedef __attribute__((ext_vector_type(8))) short bfrag;   // 8 bf16 = 4 VGPRs
typedef __attribute__((ext_vector_type(4))) float ffrag;   // 4 fp32 acc

typedef const __attribute__((address_space(1))) unsigned int* gas_t;
typedef __attribute__((address_space(3))) unsigned int* las_t;

__device__ __forceinline__ unsigned short bf16bits(float f) {
    __hip_bfloat16 b = __float2bfloat16(f);   // RNE
    return *(unsigned short*)&b;
}
__device__ __forceinline__ unsigned pack2(float a, float b) {
    return (unsigned)bf16bits(a) | ((unsigned)bf16bits(b) << 16);
}
__device__ __forceinline__ float bflo(unsigned u) {
    union { unsigned i; float f; } c; c.i = u << 16; return c.f;
}
__device__ __forceinline__ float bfhi(unsigned u) {
    union { unsigned i; float f; } c; c.i = u & 0xffff0000u; return c.f;
}
__device__ __forceinline__ void load_lds16(const float* g, float* l) {
    __builtin_amdgcn_global_load_lds((gas_t)g, (las_t)l, 16, 0, 0);
}

// ---- prep: pack B (256x128) into fragment-ordered bf16; pack w2 bf16 ----
// Bf[tn][ks][lane][j]: n = tn*16+(lane&15), k = ks*32+(lane>>4)*8+j
__global__ __launch_bounds__(256) void prep_w1_kernel(
    const float* __restrict__ w1, const float* __restrict__ w2,
    unsigned short* __restrict__ Bf, unsigned short* __restrict__ w2bf)
{
    const int gid = blockIdx.x * 256 + threadIdx.x;
    if (gid >= 4096) {
        const int j = gid - 4096;
        if (j < HD) w2bf[j] = bf16bits(w2[j]);
        return;
    }
    const int lane = gid & 63;
    const int ks   = (gid >> 6) & 7;
    const int tn   = gid >> 9;

    const int n     = tn * 16 + (lane & 15);
    const int kbase = ks * 32 + (lane >> 4) * 8;
    const int col   = n & 63;

    uint4 u;
    unsigned p[4];
    #pragma unroll
    for (int jp = 0; jp < 4; ++jp) {
        float v[2];
        #pragma unroll
        for (int h = 0; h < 2; ++h) {
            const int k = kbase + jp * 2 + h;
            const int row = ((k >= 128) ? 256 : 0) + ((n >= 64) ? 128 : 0) + (k & 127);
            v[h] = w1[(size_t)row * HD + col];
        }
        p[jp] = pack2(v[0], v[1]);
    }
    u.x = p[0]; u.y = p[1]; u.z = p[2]; u.w = p[3];
    *(uint4*)(Bf + (size_t)gid * 8) = u;
}

// ---- phase 1: MFMA GEMM with async fragment-ordered staging ----
// grid = 6250 (16 rows/block), block = 256 = 4 waves.
// Wave w: P-cols [32w, 32w+32) (tn = 2w, 2w+1). A shared via LDS.
__global__ __launch_bounds__(256) void node_gemm_mfma(
    const float* __restrict__ in1,
    const float* __restrict__ in2,
    const unsigned short* __restrict__ Bf,
    const float* __restrict__ b1,
    unsigned short* __restrict__ Pn)         // [NN][128] bf16
{
    __shared__ float staged[4096];           // 16 KB fp32 A; reused for epilogue

    const int t    = threadIdx.x;
    const int lane = t & 63;
    const int w    = t >> 6;
    const int m0   = blockIdx.x * 16;
    const int m    = lane & 15;
    const int quad = lane >> 4;

    // ---- async staging: wave w stages chunks w*4 .. w*4+3 ----
    // chunk c = 2*ks + half: slot lane holds row m, cols ks*32+quad*8+half*4
    #pragma unroll
    for (int i = 0; i < 4; ++i) {
        const int c    = w * 4 + i;
        const int ks   = c >> 1;
        const int half = c & 1;
        const int col  = ks * 32 + quad * 8 + half * 4;   // 0..255
        const float* src = (ks < 4)
            ? in1 + (size_t)(m0 + m) * DF + col
            : in2 + (size_t)(m0 + m) * DF + (col - 128);
        load_lds16(src, &staged[c * 256 + lane * 4]);
    }

    // ---- weight frags: 2 tiles x 8 ks, loaded once (L2-hot) ----
    bfrag bfr[2][8];
    #pragma unroll
    for (int ti = 0; ti < 2; ++ti) {
        const int tn = w * 2 + ti;
        #pragma unroll
        for (int ks = 0; ks < 8; ++ks)
            bfr[ti][ks] = *(const bfrag*)(Bf + ((size_t)(tn * 8 + ks) * 64 + lane) * 8);
    }

    __syncthreads();   // drains vmcnt (global_load_lds) + lgkm

    // ---- A readback (dense lane*16 pattern) + cvt + MFMA ----
    ffrag acc[2] = {{0.f, 0.f, 0.f, 0.f}, {0.f, 0.f, 0.f, 0.f}};
    #pragma unroll
    for (int ks = 0; ks < 8; ++ks) {
        const float4 lo = *(const float4*)&staged[(2 * ks) * 256 + lane * 4];
        const float4 hi = *(const float4*)&staged[(2 * ks + 1) * 256 + lane * 4];
        bfrag af;
        uint4* au = (uint4*)&af;
        au->x = pack2(lo.x, lo.y); au->y = pack2(lo.z, lo.w);
        au->z = pack2(hi.x, hi.y); au->w = pack2(hi.z, hi.w);
        acc[0] = __builtin_amdgcn_mfma_f32_16x16x32_bf16(af, bfr[0][ks], acc[0], 0, 0, 0);
        acc[1] = __builtin_amdgcn_mfma_f32_16x16x32_bf16(af, bfr[1][ks], acc[1], 0, 0, 0);
    }

    // ---- epilogue: +b1 (cols<64), bf16, LDS transpose, coalesced store ----
    __syncthreads();   // all staged reads done; safe to reuse as epilogue buf
    unsigned short* ep = (unsigned short*)staged;   // 16 x 128 bf16 = 4 KB
    {
        const int col = lane & 15;   // col-within-tile (D: col = lane&15)
        const int rq  = lane >> 4;   // D: row = rq*4 + reg
        #pragma unroll
        for (int ti = 0; ti < 2; ++ti) {
            const int nc = (w * 2 + ti) * 16 + col;
            const float badd = (w < 2) ? b1[nc] : 0.f;
            #pragma unroll
            for (int reg = 0; reg < 4; ++reg)
                ep[(rq * 4 + reg) * 128 + nc] = bf16bits(acc[ti][reg] + badd);
        }
    }
    __syncthreads();
    {
        const int row = t >> 4;
        const int seg = t & 15;
        const uint4 u = *(const uint4*)(&ep[row * 128 + seg * 8]);
        *(uint4*)(Pn + (size_t)(m0 + row) * 128 + seg * 8) = u;
    }
}

// ---- phase 2: out[s] = w2bf . relu(u'[src] + v[dst]) ----
// grid = 7813 (x32 samples, last clamped), block = 256.
// 8 lanes/sample, 8 cols/lane; 4 VMEM per thread (ts, u, v, w2).
__global__ __launch_bounds__(256) void edge_mlp_kernel(
    const unsigned short* __restrict__ Pn,
    const int*   __restrict__ ts,     // train_sample, int32
    const unsigned short* __restrict__ w2bf,   // 64 bf16
    float* __restrict__ out)          // (250000)
{
    const int t  = threadIdx.x;
    const int sr = blockIdx.x * 32 + (t >> 3);
    const int s  = min(sr, NS - 1);
    const int l  = t & 7;
    const int j  = l * 8;

    const int2 e = ((const int2*)ts)[s];
    const uint4 uu = *(const uint4*)(Pn + (size_t)e.x * 128 + j);       // u'+b1
    const uint4 vv = *(const uint4*)(Pn + (size_t)e.y * 128 + 64 + j);  // v
    const uint4 ww = *(const uint4*)(w2bf + j);

    float p = 0.f, x;
    x = bflo(uu.x) + bflo(vv.x); x = x > 0.f ? x : 0.f; p += x * bflo(ww.x);
    x = bfhi(uu.x) + bfhi(vv.x); x = x > 0.f ? x : 0.f; p += x * bfhi(ww.x);
    x = bflo(uu.y) + bflo(vv.y); x = x > 0.f ? x : 0.f; p += x * bflo(ww.y);
    x = bfhi(uu.y) + bfhi(vv.y); x = x > 0.f ? x : 0.f; p += x * bfhi(ww.y);
    x = bflo(uu.z) + bflo(vv.z); x = x > 0.f ? x : 0.f; p += x * bflo(ww.z);
    x = bfhi(uu.z) + bfhi(vv.z); x = x > 0.f ? x : 0.f; p += x * bfhi(ww.z);
    x = bflo(uu.w) + bflo(vv.w); x = x > 0.f ? x : 0.f; p += x * bflo(ww.w);
    x = bfhi(uu.w) + bfhi(vv.w); x = x > 0.f ? x : 0.f; p += x * bfhi(ww.w);

    p += __shfl_xor(p, 1);
    p += __shfl_xor(p, 2);
    p += __shfl_xor(p, 4);
    if (l == 0 && sr < NS) out[sr] = p;
}

extern "C" void kernel_launch(void* const* d_in, const int* in_sizes, int n_in,
                              void* d_out, int out_size, void* d_ws, size_t ws_size,
                              hipStream_t stream) {
    const float* in1 = (const float*)d_in[0];
    const float* in2 = (const float*)d_in[1];
    const int*   ts  = (const int*)  d_in[2];
    const float* w1  = (const float*)d_in[3];
    const float* b1  = (const float*)d_in[4];
    const float* w2  = (const float*)d_in[5];
    float* out = (float*)d_out;

    unsigned short* Pn = (unsigned short*)d_ws;     // 100000*128*2 = 25.6 MB
    const size_t Pbytes = (size_t)NN * 128 * sizeof(unsigned short);
    unsigned short* Bf;                             // 64 KB packed-B fragments
    unsigned short* w2bf;                           // 128 B packed w2
    if (ws_size >= Pbytes + 65536 + 128) {
        Bf   = (unsigned short*)((char*)d_ws + Pbytes);
        w2bf = (unsigned short*)((char*)d_ws + Pbytes + 65536);
    } else {
        // fallback: borrow d_out front (1 MB; fully overwritten by phase 2)
        Bf   = (unsigned short*)d_out;
        w2bf = (unsigned short*)((char*)d_out + 65536);
    }

    prep_w1_kernel<<<17, 256, 0, stream>>>(w1, w2, Bf, w2bf);
    node_gemm_mfma<<<NN / 16, 256, 0, stream>>>(in1, in2, Bf, b1, Pn);
    edge_mlp_kernel<<<(NS + 31) / 32, 256, 0, stream>>>(Pn, ts, w2bf, out);
}

// Round 11
// 148.904 us; speedup vs baseline: 1.2357x; 1.0812x over previous
//
#include <hip/hip_runtime.h>
#include <hip/hip_bf16.h>

// Problem constants (from reference)
#define NN  100000   // nodes
#define DF  128      // feature dim per table
#define HD  64       // hidden dim
#define NS  250000   // samples

// ---------------------------------------------------------------------------
// Algebra (R6/R8): out[s] = w2 . relu(u'[src] + v[dst]), where
//   Pn = [in1|in2] @ B  (M=100000, K=256, N=128), bf16 (25.6 MB, L3-resident)
//   Pn[n][0:64]  = u'[n] = in1[n]@W1a + in2[n]@W1c + b1   (b1 folded)
//   Pn[n][64:128]= v [n] = in1[n]@W1b + in2[n]@W1d
//   B[k][n] = w1[(k>=128)*256 + (n>=64)*128 + (k&127)][n&63]
//
// R11: software-pipelined persistent GEMM. R5-R10 evidence: every
// coalesced-staged variant = 43-44us with all pipes idle; the invariant is
// __syncthreads draining vmcnt(0) per tile (m97-plateau mechanism). Fix:
//  - 1250 blocks x 5 tiles of 16 rows; tile i+1 global loads issued before
//    tile i's pack (compiler emits partial vmcnt waits -> loads in flight
//    across the barrier)
//  - raw s_waitcnt(lgkmcnt 0) + s_barrier instead of __syncthreads
//  - A-LDS double-buffered; epilogue is wave-private (own LDS region,
//    same-wave ds ordering, no barrier)
//  => exactly ONE barrier per tile, and it never waits on global loads.
//
// Verified MFMA layouts (gfx950, learn_hip m89/m91; R6-validated here):
//   A-frag: A[m=lane&15][k=(lane>>4)*8+j]   B-frag: B[n=lane&15][k=...]
//   C/D   : col=lane&15 (B/n side), row=(lane>>4)*4+reg (A/m side)
// LESSONS: train_sample is int32 on device; NS%32=16 -> clamp+predicate;
// ~75 us of wall is harness reset overhead (input restore + ws fill).
// R9/R10 lesson: any lane->row-major mapping that puts different rows in
// different lanes of ONE load instruction scatters 16 lines -> regression.
// ---------------------------------------------------------------------------

typedef __attribute__((ext_vector_type(8))) short bfrag;   // 8 bf16 = 4 VGPRs
typedef __attribute__((ext_vector_type(4))) float ffrag;   // 4 fp32 acc

__device__ __forceinline__ unsigned short bf16bits(float f) {
    __hip_bfloat16 b = __float2bfloat16(f);   // RNE
    return *(unsigned short*)&b;
}
__device__ __forceinline__ unsigned pack2(float a, float b) {
    return (unsigned)bf16bits(a) | ((unsigned)bf16bits(b) << 16);
}
__device__ __forceinline__ float bflo(unsigned u) {
    union { unsigned i; float f; } c; c.i = u << 16; return c.f;
}
__device__ __forceinline__ float bfhi(unsigned u) {
    union { unsigned i; float f; } c; c.i = u & 0xffff0000u; return c.f;
}
// lgkmcnt(0) only; vmcnt/expcnt left at max (gfx9 encoding:
// vmcnt[3:0]|expcnt[6:4]|lgkmcnt[11:8]|vmcnt[15:14]) = 0xC07F
__device__ __forceinline__ void barrier_lgkm_only() {
    __builtin_amdgcn_s_waitcnt(0xC07F);
    __builtin_amdgcn_s_barrier();
}

// ---- prep: pack B (256x128) into fragment-ordered bf16; pack w2 bf16 ----
// Bf[tn][ks][lane][j]: n = tn*16+(lane&15), k = ks*32+(lane>>4)*8+j
__global__ __launch_bounds__(256) void prep_w1_kernel(
    const float* __restrict__ w1, const float* __restrict__ w2,
    unsigned short* __restrict__ Bf, unsigned short* __restrict__ w2bf)
{
    const int gid = blockIdx.x * 256 + threadIdx.x;
    if (gid >= 4096) {
        const int j = gid - 4096;
        if (j < HD) w2bf[j] = bf16bits(w2[j]);
        return;
    }
    const int lane = gid & 63;
    const int ks   = (gid >> 6) & 7;
    const int tn   = gid >> 9;

    const int n     = tn * 16 + (lane & 15);
    const int kbase = ks * 32 + (lane >> 4) * 8;
    const int col   = n & 63;

    uint4 u;
    unsigned p[4];
    #pragma unroll
    for (int jp = 0; jp < 4; ++jp) {
        float v[2];
        #pragma unroll
        for (int h = 0; h < 2; ++h) {
            const int k = kbase + jp * 2 + h;
            const int row = ((k >= 128) ? 256 : 0) + ((n >= 64) ? 128 : 0) + (k & 127);
            v[h] = w1[(size_t)row * HD + col];
        }
        p[jp] = pack2(v[0], v[1]);
    }
    u.x = p[0]; u.y = p[1]; u.z = p[2]; u.w = p[3];
    *(uint4*)(Bf + (size_t)gid * 8) = u;
}

#define NTILE 5      // tiles per block
#define NBLK  (NN / (16 * NTILE))   // 1250

// ---- phase 1: pipelined persistent MFMA GEMM ----
// grid = 1250, block = 256 = 4 waves. Block b: tiles b*5 .. b*5+4 (16 rows ea).
// Wave w: P-cols [32w, 32w+32).
__global__ __launch_bounds__(256) void node_gemm_mfma(
    const float* __restrict__ in1,
    const float* __restrict__ in2,
    const unsigned short* __restrict__ Bf,
    const float* __restrict__ b1,
    unsigned short* __restrict__ Pn)         // [NN][128] bf16
{
    // LDS: A double-buffer 2 x 4096 shorts (8 KB each) + per-wave epilogue
    // regions 4 x 576 shorts (16 rows x 36, +4 pad) = 20.5 KB total.
    __shared__ unsigned short smem[8192 + 4 * 576];

    const int t    = threadIdx.x;
    const int lane = t & 63;
    const int w    = t >> 6;

    // staging role: thread t stages row r's 16-float chunk qq of [in1|in2]
    const int r  = t >> 4;
    const int qq = t & 15;

    // ---- weight frags: 2 tiles x 8 ks, loaded once per block (L2-hot) ----
    bfrag bfr[2][8];
    #pragma unroll
    for (int ti = 0; ti < 2; ++ti) {
        const int tn = w * 2 + ti;
        #pragma unroll
        for (int ks = 0; ks < 8; ++ks)
            bfr[ti][ks] = *(const bfrag*)(Bf + ((size_t)(tn * 8 + ks) * 64 + lane) * 8);
    }
    // b1 fold (cols < 64 <=> waves 0,1)
    float badd[2];
    #pragma unroll
    for (int ti = 0; ti < 2; ++ti) {
        const int nc = w * 32 + ti * 16 + (lane & 15);
        badd[ti] = (w < 2) ? b1[nc] : 0.f;
    }

    const int tile0 = blockIdx.x * NTILE;

    // ---- prefetch tile 0 ----
    float4 f0, f1, f2, f3;
    {
        const int row = (tile0)*16 + r;
        const float* src = (qq < 8)
            ? in1 + (size_t)row * DF + qq * 16
            : in2 + (size_t)row * DF + (qq - 8) * 16;
        f0 = *(const float4*)(src);
        f1 = *(const float4*)(src + 4);
        f2 = *(const float4*)(src + 8);
        f3 = *(const float4*)(src + 12);
    }

    #pragma unroll
    for (int it = 0; it < NTILE; ++it) {
        const int m0 = (tile0 + it) * 16;

        // ---- issue next tile's loads FIRST (stay in flight across barrier)
        float4 g0, g1, g2, g3;
        {
            const int nt  = (it + 1 < NTILE) ? (tile0 + it + 1) : tile0; // clamp
            const int row = nt * 16 + r;
            const float* src = (qq < 8)
                ? in1 + (size_t)row * DF + qq * 16
                : in2 + (size_t)row * DF + (qq - 8) * 16;
            g0 = *(const float4*)(src);
            g1 = *(const float4*)(src + 4);
            g2 = *(const float4*)(src + 8);
            g3 = *(const float4*)(src + 12);
        }

        // ---- pack current tile -> A frags in LDS buf (it&1) ----
        unsigned short* abuf = &smem[(it & 1) * 4096];
        {
            uint4 u0, u1;
            u0.x = pack2(f0.x, f0.y); u0.y = pack2(f0.z, f0.w);
            u0.z = pack2(f1.x, f1.y); u0.w = pack2(f1.z, f1.w);
            u1.x = pack2(f2.x, f2.y); u1.y = pack2(f2.z, f2.w);
            u1.z = pack2(f3.x, f3.y); u1.w = pack2(f3.z, f3.w);
            const int g0i = qq * 2, g1i = qq * 2 + 1;
            *(uint4*)(&abuf[(g0i >> 2) * 512 + ((g0i & 3) * 16 + r) * 8]) = u0;
            *(uint4*)(&abuf[(g1i >> 2) * 512 + ((g1i & 3) * 16 + r) * 8]) = u1;
        }

        // ---- barrier: waits LDS writes only, NOT the prefetch loads ----
        barrier_lgkm_only();

        // ---- A frags + MFMA ----
        ffrag acc[2] = {{0.f, 0.f, 0.f, 0.f}, {0.f, 0.f, 0.f, 0.f}};
        #pragma unroll
        for (int ks = 0; ks < 8; ++ks) {
            const bfrag af = *(const bfrag*)(&abuf[ks * 512 + lane * 8]);
            acc[0] = __builtin_amdgcn_mfma_f32_16x16x32_bf16(af, bfr[0][ks], acc[0], 0, 0, 0);
            acc[1] = __builtin_amdgcn_mfma_f32_16x16x32_bf16(af, bfr[1][ks], acc[1], 0, 0, 0);
        }

        // ---- wave-private epilogue: transpose in own LDS region, store ----
        {
            unsigned short* ep = &smem[8192 + w * 576];   // 16 rows x 36
            const int col = lane & 15;
            const int rq  = lane >> 4;
            #pragma unroll
            for (int ti = 0; ti < 2; ++ti) {
                #pragma unroll
                for (int reg = 0; reg < 4; ++reg)
                    ep[(rq * 4 + reg) * 36 + ti * 16 + col] =
                        bf16bits(acc[ti][reg] + badd[ti]);
            }
            // same-wave ds_write -> ds_read: hw lgkmcnt ordering, no barrier
            const int rowm = lane >> 2;        // 0..15
            const int seg  = lane & 3;         // 0..3 (8 cols each)
            const uint4 u = *(const uint4*)(&ep[rowm * 36 + seg * 8]);
            *(uint4*)(Pn + (size_t)(m0 + rowm) * 128 + w * 32 + seg * 8) = u;
        }

        f0 = g0; f1 = g1; f2 = g2; f3 = g3;
    }
}

// ---- phase 2: out[s] = w2bf . relu(u'[src] + v[dst]) ----
// grid = 7813 (x32 samples, last clamped), block = 256.
// 8 lanes/sample, 8 cols/lane; 4 VMEM per thread (ts, u, v, w2).
__global__ __launch_bounds__(256) void edge_mlp_kernel(
    const unsigned short* __restrict__ Pn,
    const int*   __restrict__ ts,     // train_sample, int32
    const unsigned short* __restrict__ w2bf,   // 64 bf16
    float* __restrict__ out)          // (250000)
{
    const int t  = threadIdx.x;
    const int sr = blockIdx.x * 32 + (t >> 3);
    const int s  = min(sr, NS - 1);
    const int l  = t & 7;
    const int j  = l * 8;

    const int2 e = ((const int2*)ts)[s];
    const uint4 uu = *(const uint4*)(Pn + (size_t)e.x * 128 + j);       // u'+b1
    const uint4 vv = *(const uint4*)(Pn + (size_t)e.y * 128 + 64 + j);  // v
    const uint4 ww = *(const uint4*)(w2bf + j);

    float p = 0.f, x;
    x = bflo(uu.x) + bflo(vv.x); x = x > 0.f ? x : 0.f; p += x * bflo(ww.x);
    x = bfhi(uu.x) + bfhi(vv.x); x = x > 0.f ? x : 0.f; p += x * bfhi(ww.x);
    x = bflo(uu.y) + bflo(vv.y); x = x > 0.f ? x : 0.f; p += x * bflo(ww.y);
    x = bfhi(uu.y) + bfhi(vv.y); x = x > 0.f ? x : 0.f; p += x * bfhi(ww.y);
    x = bflo(uu.z) + bflo(vv.z); x = x > 0.f ? x : 0.f; p += x * bflo(ww.z);
    x = bfhi(uu.z) + bfhi(vv.z); x = x > 0.f ? x : 0.f; p += x * bfhi(ww.z);
    x = bflo(uu.w) + bflo(vv.w); x = x > 0.f ? x : 0.f; p += x * bflo(ww.w);
    x = bfhi(uu.w) + bfhi(vv.w); x = x > 0.f ? x : 0.f; p += x * bfhi(ww.w);

    p += __shfl_xor(p, 1);
    p += __shfl_xor(p, 2);
    p += __shfl_xor(p, 4);
    if (l == 0 && sr < NS) out[sr] = p;
}

extern "C" void kernel_launch(void* const* d_in, const int* in_sizes, int n_in,
                              void* d_out, int out_size, void* d_ws, size_t ws_size,
                              hipStream_t stream) {
    const float* in1 = (const float*)d_in[0];
    const float* in2 = (const float*)d_in[1];
    const int*   ts  = (const int*)  d_in[2];
    const float* w1  = (const float*)d_in[3];
    const float* b1  = (const float*)d_in[4];
    const float* w2  = (const float*)d_in[5];
    float* out = (float*)d_out;

    unsigned short* Pn = (unsigned short*)d_ws;     // 100000*128*2 = 25.6 MB
    const size_t Pbytes = (size_t)NN * 128 * sizeof(unsigned short);
    unsigned short* Bf;                             // 64 KB packed-B fragments
    unsigned short* w2bf;                           // 128 B packed w2
    if (ws_size >= Pbytes + 65536 + 128) {
        Bf   = (unsigned short*)((char*)d_ws + Pbytes);
        w2bf = (unsigned short*)((char*)d_ws + Pbytes + 65536);
    } else {
        // fallback: borrow d_out front (1 MB; fully overwritten by phase 2)
        Bf   = (unsigned short*)d_out;
        w2bf = (unsigned short*)((char*)d_out + 65536);
    }

    prep_w1_kernel<<<17, 256, 0, stream>>>(w1, w2, Bf, w2bf);
    node_gemm_mfma<<<NBLK, 256, 0, stream>>>(in1, in2, Bf, b1, Pn);
    edge_mlp_kernel<<<(NS + 31) / 32, 256, 0, stream>>>(Pn, ts, w2bf, out);
}

// Round 12
// 146.400 us; speedup vs baseline: 1.2569x; 1.0171x over previous
//
#include <hip/hip_runtime.h>
#include <hip/hip_bf16.h>

// Problem constants (from reference)
#define NN  100000   // nodes
#define DF  128      // feature dim per table
#define HD  64       // hidden dim
#define NS  250000   // samples

// ---------------------------------------------------------------------------
// Algebra (R6/R8): out[s] = w2 . relu(u'[src] + v[dst]), where
//   Pn = [in1|in2] @ B  (M=100000, K=256, N=128), bf16 (25.6 MB, L3-resident)
//   Pn[n][0:64]  = u'[n] = in1[n]@W1a + in2[n]@W1c + b1   (b1 folded)
//   Pn[n][64:128]= v [n] = in1[n]@W1b + in2[n]@W1d
//
// R12: gemm/prep frozen (R11). Edge rewritten for MLP: cross-round
// bookkeeping (fixed overhead ~34us from R3) says edge ~65-70us and was
// insensitive to traffic cuts (R6: 4x fewer bytes, ~same time) -> bound by
// the ts->gather dependency chain + random-line rate, not bytes. New edge:
// persistent 1024 blocks x 4 passes, 4 lanes/sample, w2 in regs, next-pass
// ts load issued before current gathers are consumed (dep chain broken).
//
// Verified MFMA layouts (gfx950, learn_hip m89/m91; R6-validated here):
//   A-frag: A[m=lane&15][k=(lane>>4)*8+j]   B-frag: B[n=lane&15][k=...]
//   C/D   : col=lane&15 (B/n side), row=(lane>>4)*4+reg (A/m side)
// LESSONS: train_sample is int32 on device; NS tail -> clamp+predicate;
// R9/R10: per-lane row-major loads scatter 16 lines/instr -> regression.
// ---------------------------------------------------------------------------

typedef __attribute__((ext_vector_type(8))) short bfrag;   // 8 bf16 = 4 VGPRs
typedef __attribute__((ext_vector_type(4))) float ffrag;   // 4 fp32 acc

__device__ __forceinline__ unsigned short bf16bits(float f) {
    __hip_bfloat16 b = __float2bfloat16(f);   // RNE
    return *(unsigned short*)&b;
}
__device__ __forceinline__ unsigned pack2(float a, float b) {
    return (unsigned)bf16bits(a) | ((unsigned)bf16bits(b) << 16);
}
__device__ __forceinline__ float bflo(unsigned u) {
    union { unsigned i; float f; } c; c.i = u << 16; return c.f;
}
__device__ __forceinline__ float bfhi(unsigned u) {
    union { unsigned i; float f; } c; c.i = u & 0xffff0000u; return c.f;
}
// lgkmcnt(0) only; vmcnt/expcnt left at max (gfx9 encoding) = 0xC07F
__device__ __forceinline__ void barrier_lgkm_only() {
    __builtin_amdgcn_s_waitcnt(0xC07F);
    __builtin_amdgcn_s_barrier();
}

// ---- prep: pack B (256x128) into fragment-ordered bf16; pack w2 bf16 ----
// Bf[tn][ks][lane][j]: n = tn*16+(lane&15), k = ks*32+(lane>>4)*8+j
__global__ __launch_bounds__(256) void prep_w1_kernel(
    const float* __restrict__ w1, const float* __restrict__ w2,
    unsigned short* __restrict__ Bf, unsigned short* __restrict__ w2bf)
{
    const int gid = blockIdx.x * 256 + threadIdx.x;
    if (gid >= 4096) {
        const int j = gid - 4096;
        if (j < HD) w2bf[j] = bf16bits(w2[j]);
        return;
    }
    const int lane = gid & 63;
    const int ks   = (gid >> 6) & 7;
    const int tn   = gid >> 9;

    const int n     = tn * 16 + (lane & 15);
    const int kbase = ks * 32 + (lane >> 4) * 8;
    const int col   = n & 63;

    uint4 u;
    unsigned p[4];
    #pragma unroll
    for (int jp = 0; jp < 4; ++jp) {
        float v[2];
        #pragma unroll
        for (int h = 0; h < 2; ++h) {
            const int k = kbase + jp * 2 + h;
            const int row = ((k >= 128) ? 256 : 0) + ((n >= 64) ? 128 : 0) + (k & 127);
            v[h] = w1[(size_t)row * HD + col];
        }
        p[jp] = pack2(v[0], v[1]);
    }
    u.x = p[0]; u.y = p[1]; u.z = p[2]; u.w = p[3];
    *(uint4*)(Bf + (size_t)gid * 8) = u;
}

#define NTILE 5      // tiles per block
#define NBLK  (NN / (16 * NTILE))   // 1250

// ---- phase 1: pipelined persistent MFMA GEMM (frozen from R11) ----
__global__ __launch_bounds__(256) void node_gemm_mfma(
    const float* __restrict__ in1,
    const float* __restrict__ in2,
    const unsigned short* __restrict__ Bf,
    const float* __restrict__ b1,
    unsigned short* __restrict__ Pn)         // [NN][128] bf16
{
    __shared__ unsigned short smem[8192 + 4 * 576];

    const int t    = threadIdx.x;
    const int lane = t & 63;
    const int w    = t >> 6;
    const int r  = t >> 4;
    const int qq = t & 15;

    bfrag bfr[2][8];
    #pragma unroll
    for (int ti = 0; ti < 2; ++ti) {
        const int tn = w * 2 + ti;
        #pragma unroll
        for (int ks = 0; ks < 8; ++ks)
            bfr[ti][ks] = *(const bfrag*)(Bf + ((size_t)(tn * 8 + ks) * 64 + lane) * 8);
    }
    float badd[2];
    #pragma unroll
    for (int ti = 0; ti < 2; ++ti) {
        const int nc = w * 32 + ti * 16 + (lane & 15);
        badd[ti] = (w < 2) ? b1[nc] : 0.f;
    }

    const int tile0 = blockIdx.x * NTILE;

    float4 f0, f1, f2, f3;
    {
        const int row = (tile0)*16 + r;
        const float* src = (qq < 8)
            ? in1 + (size_t)row * DF + qq * 16
            : in2 + (size_t)row * DF + (qq - 8) * 16;
        f0 = *(const float4*)(src);
        f1 = *(const float4*)(src + 4);
        f2 = *(const float4*)(src + 8);
        f3 = *(const float4*)(src + 12);
    }

    #pragma unroll
    for (int it = 0; it < NTILE; ++it) {
        const int m0 = (tile0 + it) * 16;

        float4 g0, g1, g2, g3;
        {
            const int nt  = (it + 1 < NTILE) ? (tile0 + it + 1) : tile0;
            const int row = nt * 16 + r;
            const float* src = (qq < 8)
                ? in1 + (size_t)row * DF + qq * 16
                : in2 + (size_t)row * DF + (qq - 8) * 16;
            g0 = *(const float4*)(src);
            g1 = *(const float4*)(src + 4);
            g2 = *(const float4*)(src + 8);
            g3 = *(const float4*)(src + 12);
        }

        unsigned short* abuf = &smem[(it & 1) * 4096];
        {
            uint4 u0, u1;
            u0.x = pack2(f0.x, f0.y); u0.y = pack2(f0.z, f0.w);
            u0.z = pack2(f1.x, f1.y); u0.w = pack2(f1.z, f1.w);
            u1.x = pack2(f2.x, f2.y); u1.y = pack2(f2.z, f2.w);
            u1.z = pack2(f3.x, f3.y); u1.w = pack2(f3.z, f3.w);
            const int g0i = qq * 2, g1i = qq * 2 + 1;
            *(uint4*)(&abuf[(g0i >> 2) * 512 + ((g0i & 3) * 16 + r) * 8]) = u0;
            *(uint4*)(&abuf[(g1i >> 2) * 512 + ((g1i & 3) * 16 + r) * 8]) = u1;
        }

        barrier_lgkm_only();

        ffrag acc[2] = {{0.f, 0.f, 0.f, 0.f}, {0.f, 0.f, 0.f, 0.f}};
        #pragma unroll
        for (int ks = 0; ks < 8; ++ks) {
            const bfrag af = *(const bfrag*)(&abuf[ks * 512 + lane * 8]);
            acc[0] = __builtin_amdgcn_mfma_f32_16x16x32_bf16(af, bfr[0][ks], acc[0], 0, 0, 0);
            acc[1] = __builtin_amdgcn_mfma_f32_16x16x32_bf16(af, bfr[1][ks], acc[1], 0, 0, 0);
        }

        {
            unsigned short* ep = &smem[8192 + w * 576];   // 16 rows x 36
            const int col = lane & 15;
            const int rq  = lane >> 4;
            #pragma unroll
            for (int ti = 0; ti < 2; ++ti) {
                #pragma unroll
                for (int reg = 0; reg < 4; ++reg)
                    ep[(rq * 4 + reg) * 36 + ti * 16 + col] =
                        bf16bits(acc[ti][reg] + badd[ti]);
            }
            const int rowm = lane >> 2;
            const int seg  = lane & 3;
            const uint4 u = *(const uint4*)(&ep[rowm * 36 + seg * 8]);
            *(uint4*)(Pn + (size_t)(m0 + rowm) * 128 + w * 32 + seg * 8) = u;
        }

        f0 = g0; f1 = g1; f2 = g2; f3 = g3;
    }
}

// ---- phase 2 (R12): persistent gather MLP, dep-chain pipelined ----
// grid = 1024 blocks x 256 threads, 4 passes. Pass p of block b handles
// samples [ (p*1024 + b)*64, +64 ): 4 lanes/sample, 16 cols/lane.
// w2 slice hoisted to regs; next pass's ts load issues before current
// gathers are consumed -> every wave keeps ~5 independent VMEM in flight.
#define EBLK   1024
#define EPASS  4     // ceil(250000 / (1024*64)) = 4
__global__ __launch_bounds__(256) void edge_mlp_kernel(
    const unsigned short* __restrict__ Pn,
    const int*   __restrict__ ts,     // train_sample, int32
    const unsigned short* __restrict__ w2bf,   // 64 bf16
    float* __restrict__ out)          // (250000)
{
    const int t = threadIdx.x;
    const int q = t & 3;          // 16-col slice: cols q*16 .. q*16+15
    const int g = t >> 2;         // sample slot 0..63

    // hoist w2 slice (32 B) into registers once
    const uint4 w0 = *(const uint4*)(w2bf + q * 16);
    const uint4 w1v = *(const uint4*)(w2bf + q * 16 + 8);

    const int2* ts2 = (const int2*)ts;

    int sr = blockIdx.x * 64 + g;             // pass 0 sample
    int2 e = ts2[min(sr, NS - 1)];

    #pragma unroll
    for (int p = 0; p < EPASS; ++p) {
        // gathers for current sample (independent 16B loads)
        const unsigned short* up = Pn + (size_t)e.x * 128 + q * 16;
        const unsigned short* vp = Pn + (size_t)e.y * 128 + 64 + q * 16;
        const uint4 u0 = *(const uint4*)(up);
        const uint4 u1 = *(const uint4*)(up + 8);
        const uint4 v0 = *(const uint4*)(vp);
        const uint4 v1 = *(const uint4*)(vp + 8);

        // issue next pass's ts load BEFORE consuming the gathers
        const int sr_n = sr + EBLK * 64;
        int2 e_n;
        if (p + 1 < EPASS) e_n = ts2[min(sr_n, NS - 1)];

        float acc = 0.f, x;
        x = bflo(u0.x) + bflo(v0.x); x = x > 0.f ? x : 0.f; acc += x * bflo(w0.x);
        x = bfhi(u0.x) + bfhi(v0.x); x = x > 0.f ? x : 0.f; acc += x * bfhi(w0.x);
        x = bflo(u0.y) + bflo(v0.y); x = x > 0.f ? x : 0.f; acc += x * bflo(w0.y);
        x = bfhi(u0.y) + bfhi(v0.y); x = x > 0.f ? x : 0.f; acc += x * bfhi(w0.y);
        x = bflo(u0.z) + bflo(v0.z); x = x > 0.f ? x : 0.f; acc += x * bflo(w0.z);
        x = bfhi(u0.z) + bfhi(v0.z); x = x > 0.f ? x : 0.f; acc += x * bfhi(w0.z);
        x = bflo(u0.w) + bflo(v0.w); x = x > 0.f ? x : 0.f; acc += x * bflo(w0.w);
        x = bfhi(u0.w) + bfhi(v0.w); x = x > 0.f ? x : 0.f; acc += x * bfhi(w0.w);
        x = bflo(u1.x) + bflo(v1.x); x = x > 0.f ? x : 0.f; acc += x * bflo(w1v.x);
        x = bfhi(u1.x) + bfhi(v1.x); x = x > 0.f ? x : 0.f; acc += x * bfhi(w1v.x);
        x = bflo(u1.y) + bflo(v1.y); x = x > 0.f ? x : 0.f; acc += x * bflo(w1v.y);
        x = bfhi(u1.y) + bfhi(v1.y); x = x > 0.f ? x : 0.f; acc += x * bfhi(w1v.y);
        x = bflo(u1.z) + bflo(v1.z); x = x > 0.f ? x : 0.f; acc += x * bflo(w1v.z);
        x = bfhi(u1.z) + bfhi(v1.z); x = x > 0.f ? x : 0.f; acc += x * bfhi(w1v.z);
        x = bflo(u1.w) + bflo(v1.w); x = x > 0.f ? x : 0.f; acc += x * bflo(w1v.w);
        x = bfhi(u1.w) + bfhi(v1.w); x = x > 0.f ? x : 0.f; acc += x * bfhi(w1v.w);

        acc += __shfl_xor(acc, 1);
        acc += __shfl_xor(acc, 2);
        if (q == 0 && sr < NS) out[sr] = acc;

        sr = sr_n;
        e  = e_n;
    }
}

extern "C" void kernel_launch(void* const* d_in, const int* in_sizes, int n_in,
                              void* d_out, int out_size, void* d_ws, size_t ws_size,
                              hipStream_t stream) {
    const float* in1 = (const float*)d_in[0];
    const float* in2 = (const float*)d_in[1];
    const int*   ts  = (const int*)  d_in[2];
    const float* w1  = (const float*)d_in[3];
    const float* b1  = (const float*)d_in[4];
    const float* w2  = (const float*)d_in[5];
    float* out = (float*)d_out;

    unsigned short* Pn = (unsigned short*)d_ws;     // 100000*128*2 = 25.6 MB
    const size_t Pbytes = (size_t)NN * 128 * sizeof(unsigned short);
    unsigned short* Bf;                             // 64 KB packed-B fragments
    unsigned short* w2bf;                           // 128 B packed w2
    if (ws_size >= Pbytes + 65536 + 128) {
        Bf   = (unsigned short*)((char*)d_ws + Pbytes);
        w2bf = (unsigned short*)((char*)d_ws + Pbytes + 65536);
    } else {
        // fallback: borrow d_out front (fully overwritten by phase 2)
        Bf   = (unsigned short*)d_out;
        w2bf = (unsigned short*)((char*)d_out + 65536);
    }

    prep_w1_kernel<<<17, 256, 0, stream>>>(w1, w2, Bf, w2bf);
    node_gemm_mfma<<<NBLK, 256, 0, stream>>>(in1, in2, Bf, b1, Pn);
    edge_mlp_kernel<<<EBLK, 256, 0, stream>>>(Pn, ts, w2bf, out);
}